// Round 5
// baseline (727.262 us; speedup 1.0000x reference)
//
#include <hip/hip_runtime.h>

// Problem constants (match reference): B=64, T=2048, H=256, A=4.
// Reference collapses exactly: out[b,t,h*A+a] = X[b,t,h] * (t>0).
// Pure streaming op: read 128 MiB + write 512 MiB = 671 MB -> ~107 us @ 6.3 TB/s.
//
// ROUND 5 = DECOMPOSITION EXPERIMENT (deliberate, not an optimization):
// rocprof shows the graded dur_us (610) includes harness fills (342 us steady
// state) and our kernel is NOT in the top-5 (so < 342 us). To separate
// fixed-harness time from kernel time, dispatch the IDENTICAL kernel TWICE
// (idempotent: second pass rewrites the same values; absmax stays 0).
//   dur_us_new - 610 = true kernel time (warm).
//   Delta ~270 -> kernel at 2.5 TB/s, 160 us headroom exists.
//   Delta ~110 -> kernel already at streaming roofline; 610 floor is harness.

#define NB 64
#define NT 2048
#define NH 256
#define N_TOTAL (NB * NT * NH)   // 33,554,432 elements (float4 outputs)

#define GRID_BLOCKS 8192

typedef float fvec4 __attribute__((ext_vector_type(4)));

__global__ __launch_bounds__(256) void attn_bcast_kernel(
    const float* __restrict__ X,   // [B*T*H] floats
    fvec4* __restrict__ out)       // [B*T*H] float4s (A=4 splat)
{
    const unsigned stride = gridDim.x * blockDim.x;
    unsigned i = blockIdx.x * blockDim.x + threadIdx.x;
    #pragma unroll 4
    for (; i < N_TOTAL; i += stride) {
        float v = __builtin_nontemporal_load(&X[i]);
        // t = (i / H) % T ; H=256 -> >>8 ; T=2048 -> &2047. Zero the t==0 slice.
        if (((i >> 8) & 2047u) == 0u) v = 0.0f;
        fvec4 o = {v, v, v, v};
        __builtin_nontemporal_store(o, &out[i]);
    }
}

extern "C" void kernel_launch(void* const* d_in, const int* in_sizes, int n_in,
                              void* d_out, int out_size, void* d_ws, size_t ws_size,
                              hipStream_t stream) {
    const float* X = (const float*)d_in[0];  // [B, T, H] float32
    // d_in[1..4] = W1, b1, W2, b2 — unused (softmax-prefix weight == (t>0)).
    fvec4* out4 = (fvec4*)d_out;

    dim3 grid(GRID_BLOCKS), block(256);
    // Dispatch TWICE, identical args, same stream (serialized). Idempotent.
    attn_bcast_kernel<<<grid, block, 0, stream>>>(X, out4);
    attn_bcast_kernel<<<grid, block, 0, stream>>>(X, out4);
}

// Round 6
// 607.089 us; speedup vs baseline: 1.1979x; 1.1979x over previous
//
#include <hip/hip_runtime.h>

// Problem constants (match reference): B=64, T=2048, H=256, A=4.
// Reference collapses exactly: out[b,t,h*A+a] = X[b,t,h] * (t>0)
// (softmax-over-prefix weight == indicator(t>0); W1/b1/W2/b2 mathematically
// cancel). Pure streaming op: read 128 MiB + write 512 MiB = 671 MB.
//
// MEASURED DECOMPOSITION (Round 5, double-dispatch experiment):
//   true kernel time      = 117.1 us  -> 5.74 TB/s = 91% of 6.3 TB/s achievable
//   fixed harness in dur  = ~493 us   (342 us output-poison fill @78% peak
//                                      + ~150 us other restore ops)
// Graded floor ~= 600 us; we measure 605-610. Kernel is at streaming roofline.

#define NB 64
#define NT 2048
#define NH 256
#define N_TOTAL (NB * NT * NH)   // 33,554,432 elements (float4 outputs)

#define GRID_BLOCKS 8192         // grid-stride, 16 elems/thread, no tail

// __builtin_nontemporal_store needs a native clang vector type (HIP float4
// is a class -> rejected). ext_vector_type(4) float works.
typedef float fvec4 __attribute__((ext_vector_type(4)));

__global__ __launch_bounds__(256) void attn_bcast_kernel(
    const float* __restrict__ X,   // [B*T*H] floats
    fvec4* __restrict__ out)       // [B*T*H] float4s (A=4 splat)
{
    const unsigned stride = gridDim.x * blockDim.x;
    unsigned i = blockIdx.x * blockDim.x + threadIdx.x;
    #pragma unroll 4
    for (; i < N_TOTAL; i += stride) {
        // Read-once / write-once streams; out (512 MiB) >> L2+L3: stay nt.
        float v = __builtin_nontemporal_load(&X[i]);
        // t = (i / H) % T ; H=256 -> >>8 ; T=2048 -> &2047. Zero the t==0 slice.
        if (((i >> 8) & 2047u) == 0u) v = 0.0f;
        fvec4 o = {v, v, v, v};
        __builtin_nontemporal_store(o, &out[i]);
    }
}

extern "C" void kernel_launch(void* const* d_in, const int* in_sizes, int n_in,
                              void* d_out, int out_size, void* d_ws, size_t ws_size,
                              hipStream_t stream) {
    const float* X = (const float*)d_in[0];  // [B, T, H] float32
    // d_in[1..4] = W1, b1, W2, b2 — unused (softmax-prefix weight == (t>0)).
    fvec4* out4 = (fvec4*)d_out;

    dim3 grid(GRID_BLOCKS), block(256);
    attn_bcast_kernel<<<grid, block, 0, stream>>>(X, out4);
}